// Round 7
// baseline (414.620 us; speedup 1.0000x reference)
//
#include <hip/hip_runtime.h>
#include <math.h>

// GlmDSAMoEGate, round 10: stop draining vmcnt at the mega-tile barrier.
// R9 (~132us kernel est.): all pipe floors ~41-49us; ~770cy/phase of stall.
// __syncthreads() emits s_waitcnt vmcnt(0) lgkmcnt(0): at each of 32 barriers
// the whole CU (1 block/CU) waits the loaded-HBM latency of the x prefetch
// issued ~50cy earlier (~900-1500cy) AND drains the B prefetch issued in
// phases 4-7 (killing next tile's phases 0-3 pipeline). T4 principle: only
// the A ds_writes need barrier visibility -> lgkmcnt(0)-only + raw s_barrier.
// x and B live in registers; the compiler inserts counted vmcnt waits at
// their first USE (~3000cy after issue for x, 4 phases for B).
// Everything else identical to R9 (passed, absmax 2e-3):
//  - BM=64, NTH=512, grid=256, 1 blk/CU; wave = 32 experts x 64 tokens.
//  - B: 4 rotating slots, prefetch distance 4 phases; sched_barrier(0)/phase.
//  - A: LDS XOR-swizzled hi/lo planes, double-buffered, read-ahead 1 phase.
//  - Epilogue: 8 threads/token, exact lax.top_k tie semantics.
// Math: fp32 -> fp16 hi + lo*2^12 split, 3 MFMA passes, logit = accA+accB*2^-12.

constexpr int H = 4096;
constexpr int E = 256;
constexpr int BM = 64;          // tokens per block
constexpr int NTH = 512;        // 8 waves
constexpr int TOPK = 8;
constexpr int NGROUP = 8;
constexpr int GSIZE = 32;
constexpr int TOPK_GROUP = 4;
constexpr float SCALE = 2.5f;
constexpr int NK16 = H / 16;    // 256 k16 slabs (global phases)
constexpr int NMT = H / 128;    // 32 K-mega-tiles
constexpr float LO_SCALE = 4096.0f;       // 2^12
constexpr float LO_INV = 1.0f / 4096.0f;  // 2^-12

typedef _Float16 f16x8 __attribute__((ext_vector_type(8)));
typedef float f32x4 __attribute__((ext_vector_type(4)));
typedef float f32x16 __attribute__((ext_vector_type(16)));

// ---------------- kernel 0: W[E][H] fp32 -> fragment-linear fp16 hi/lo ------
// Frag for MFMA 32x32x16 tile (k16, n32): lane l holds B[k][n] with
// n = n32*32 + (l&31), k = k16*16 + (l>>5)*8 + j, j=0..7  (16B per lane).
// Layout: wswz[(k16*8 + n32)*1024 + hl*512 + l*8]  (halves). Total 4MB.
__global__ __launch_bounds__(64)
void prep_w_kernel(const float* __restrict__ w, _Float16* __restrict__ wswz) {
  const int l = threadIdx.x;        // 0..63
  const int k16 = blockIdx.x;       // 0..255
  const int n32 = blockIdx.y;       // 0..7
  const int e = n32 * 32 + (l & 31);
  const int h0 = k16 * 16 + (l >> 5) * 8;
  const float4* wp = (const float4*)(w + (size_t)e * H + h0);
  const float4 a = wp[0], b = wp[1];
  const float v[8] = {a.x, a.y, a.z, a.w, b.x, b.y, b.z, b.w};
  f16x8 hi, lo;
#pragma unroll
  for (int j = 0; j < 8; ++j) {
    const _Float16 h = (_Float16)v[j];
    hi[j] = h;
    lo[j] = (_Float16)((v[j] - (float)h) * LO_SCALE);  // exact residual, scaled
  }
  _Float16* dst = wswz + (size_t)(k16 * 8 + n32) * 1024 + (size_t)l * 8;
  *(f16x8*)dst = hi;
  *(f16x8*)(dst + 512) = lo;
}

// ---------------- kernel 1: fused gate -------------------------------------
__global__ __launch_bounds__(NTH, 2)
void moe_gate_kernel(const float* __restrict__ x,      // [T][H] fp32
                     const _Float16* __restrict__ wswz,// frag-linear hi/lo
                     const float* __restrict__ bias,   // [E]
                     float* __restrict__ out_idx,      // [T][8] (as float)
                     float* __restrict__ out_w) {      // [T][8]
  // a: [buf][s 0..7][mt 0..1][hl][512 halves] = 64 KB
  // val: scores_for_choice, 64*257*4 = 65792 B.  Disjoint in time -> union.
  __shared__ __align__(16) union SM {
    _Float16 a[2][8][2][2][512];
    float val[BM][E + 1];
  } sm;
  __shared__ float sbias[E];

  const int tid = threadIdx.x;
  const int lane = tid & 63;
  const int wave = tid >> 6;         // 0..7 -> expert slice [32*wave, +32)
  const long t0 = (long)blockIdx.x * BM;

  if (tid < E) sbias[tid] = bias[tid];

  // A staging coords (per 32-token half): thread -> (token ta, k-octet ko),
  // 8 floats = 32B of x. Chunk c = kh*32 + ta (kh = ko&1), phase s = ko>>1.
  // Write pos = c ^ s, read pos = lane ^ s (XOR swizzle, conflict-free reads).
  const int ta = tid >> 4;           // 0..31 token (half 0); half 1 = ta+32
  const int ko = tid & 15;           // 0..15 k-octet within 128-k mega-tile
  const int sA = ko >> 1;            // k16 phase 0..7
  const int posA = (((ko & 1) << 5) | ta) ^ sA;
  const float* xp0 = x + (size_t)(t0 + ta) * H + ko * 8;        // token ta
  const float* xp1 = xp0 + (size_t)32 * H;                      // token ta+32

  // B frag base for this wave/lane; per-k16 stride = 8192 halves
  const _Float16* const bb = wswz + (size_t)wave * 1024 + (size_t)lane * 8;

  f32x16 accA[2], accB[2];           // [mt] - 64 VGPR
#pragma unroll
  for (int mt = 0; mt < 2; ++mt)
#pragma unroll
    for (int r = 0; r < 16; ++r) { accA[mt][r] = 0.0f; accB[mt][r] = 0.0f; }

  f16x8 B[4][2];                     // 4 rotating phase slots x {hi,lo} = 32 VGPR

  auto writeA = [&](int buf, int mt, f32x4 qa, f32x4 qb) {
    const float v[8] = {qa[0], qa[1], qa[2], qa[3], qb[0], qb[1], qb[2], qb[3]};
    f16x8 hv, lv;
#pragma unroll
    for (int j = 0; j < 8; ++j) {
      const _Float16 h = (_Float16)v[j];
      hv[j] = h;
      lv[j] = (_Float16)((v[j] - (float)h) * LO_SCALE);
    }
    _Float16* p = &sm.a[buf][sA][mt][0][posA * 8];
    *(f16x8*)p = hv;
    *(f16x8*)(p + 512) = lv;         // hl stride = 512 halves
  };

  // ---- prologue: A mega-tile 0 staged into buf 0, B phases 0-3 into slots ----
  {
    const f32x4 q0 = __builtin_nontemporal_load((const f32x4*)xp0);
    const f32x4 q1 = __builtin_nontemporal_load((const f32x4*)xp0 + 1);
    const f32x4 q2 = __builtin_nontemporal_load((const f32x4*)xp1);
    const f32x4 q3 = __builtin_nontemporal_load((const f32x4*)xp1 + 1);
    writeA(0, 0, q0, q1);
    writeA(0, 1, q2, q3);
#pragma unroll
    for (int s = 0; s < 4; ++s) {
      const _Float16* bp = bb + (size_t)s * 8192;
      B[s][0] = *(const f16x8*)bp;
      B[s][1] = *(const f16x8*)(bp + 512);
    }
  }

  // ---- main loop: 32 mega-tiles, 1 lgkm-only barrier each ----
#pragma unroll 1
  for (int mt = 0; mt < NMT; ++mt) {
    const int buf = mt & 1;
    const bool more = (mt + 1 < NMT);
    f32x4 q0 = {}, q1 = {}, q2 = {}, q3 = {};
    if (more) {                      // x for mt+1: issue BEFORE the barrier
      xp0 += 128;
      xp1 += 128;
      q0 = __builtin_nontemporal_load((const f32x4*)xp0);
      q1 = __builtin_nontemporal_load((const f32x4*)xp0 + 1);
      q2 = __builtin_nontemporal_load((const f32x4*)xp1);
      q3 = __builtin_nontemporal_load((const f32x4*)xp1 + 1);
    }
    // T4: barrier with LGKM drain only. ds_writes become visible; x/B vmem
    // loads (register dests) stay IN FLIGHT across the barrier. Each wave's
    // ds_reads of the outgoing buffer were already lgkm-waited before use.
    asm volatile("s_waitcnt lgkmcnt(0)\n\ts_barrier" ::: "memory");

    f16x8 af[2][2][2];               // [par][mt][hl] read-ahead sets, static idx
    {
      const int pos0 = (lane ^ 0) * 8;
      af[0][0][0] = *(const f16x8*)&sm.a[buf][0][0][0][pos0];
      af[0][0][1] = *(const f16x8*)&sm.a[buf][0][0][1][pos0];
      af[0][1][0] = *(const f16x8*)&sm.a[buf][0][1][0][pos0];
      af[0][1][1] = *(const f16x8*)&sm.a[buf][0][1][1][pos0];
    }
#pragma unroll
    for (int s = 0; s < 8; ++s) {    // all indices compile-time after unroll
      const int par = s & 1, nxt = par ^ 1, slot = s & 3;
      if (s < 7) {                   // read-ahead phase s+1 A-frags
        const int pos = (lane ^ (s + 1)) * 8;
        af[nxt][0][0] = *(const f16x8*)&sm.a[buf][s + 1][0][0][pos];
        af[nxt][0][1] = *(const f16x8*)&sm.a[buf][s + 1][0][1][pos];
        af[nxt][1][0] = *(const f16x8*)&sm.a[buf][s + 1][1][0][pos];
        af[nxt][1][1] = *(const f16x8*)&sm.a[buf][s + 1][1][1][pos];
      }
      __builtin_amdgcn_s_setprio(1);
      accA[0] = __builtin_amdgcn_mfma_f32_32x32x16_f16(af[par][0][0], B[slot][0], accA[0], 0, 0, 0);
      accA[1] = __builtin_amdgcn_mfma_f32_32x32x16_f16(af[par][1][0], B[slot][0], accA[1], 0, 0, 0);
      accB[0] = __builtin_amdgcn_mfma_f32_32x32x16_f16(af[par][0][0], B[slot][1], accB[0], 0, 0, 0);
      accB[1] = __builtin_amdgcn_mfma_f32_32x32x16_f16(af[par][1][0], B[slot][1], accB[1], 0, 0, 0);
      accB[0] = __builtin_amdgcn_mfma_f32_32x32x16_f16(af[par][0][1], B[slot][0], accB[0], 0, 0, 0);
      accB[1] = __builtin_amdgcn_mfma_f32_32x32x16_f16(af[par][1][1], B[slot][0], accB[1], 0, 0, 0);
      __builtin_amdgcn_s_setprio(0);
      // prefetch global phase 8*mt+s+4 into the just-freed slot
      // (branchless tail clamp: redundant loads at the end, never consumed)
      const int gp = 8 * mt + s + 4;
      const int gpc = gp < NK16 ? gp : NK16 - 1;
      const _Float16* bp = bb + (size_t)gpc * 8192;
      B[slot][0] = *(const f16x8*)bp;
      B[slot][1] = *(const f16x8*)(bp + 512);
      __builtin_amdgcn_sched_barrier(0);  // pin phase schedule
    }
    if (more) {
      writeA(buf ^ 1, 0, q0, q1);
      writeA(buf ^ 1, 1, q2, q3);
    }
  }

  // ---- scores_for_choice into LDS (val overlays a_st: full barrier first) ----
  __syncthreads();
  // C layout (32x32 MFMA): col = lane&31, row = (r&3) + 8*(r>>2) + 4*(lane>>5)
  {
    const int col = lane & 31;
    const int rbase = (lane >> 5) * 4;
    const int e = wave * 32 + col;
    const float be = sbias[e];
#pragma unroll
    for (int mt = 0; mt < 2; ++mt)
#pragma unroll
      for (int r = 0; r < 16; ++r) {
        const int row = (r & 3) + 8 * (r >> 2) + rbase;
        const float logit = accA[mt][r] + accB[mt][r] * LO_INV;
        const float s = 1.0f / (1.0f + expf(-logit));    // sigmoid
        sm.val[mt * 32 + row][e] = s + be;               // s_choice
      }
  }
  __syncthreads();

  // ---- grouped top-k, 8 threads per token (exact lax.top_k semantics) ----
  {
    const int tok = tid >> 3;        // 0..63
    const int tpt = tid & 7;         // sub-lane == group g; experts [32*tpt,+32)
    const int base = lane & ~7;      // wave-lane base of this token's 8-cluster

    // cache my group's 32 experts in registers
    float lv[GSIZE];
#pragma unroll
    for (int j = 0; j < GSIZE; ++j) lv[j] = sm.val[tok][tpt * GSIZE + j];

    // group top-2 sum, fully local (one group per sub-lane)
    float m1 = -1e30f, m2 = -1e30f;
#pragma unroll
    for (int j = 0; j < GSIZE; ++j) {
      const float v = lv[j];
      if (v > m1) { m2 = m1; m1 = v; }
      else if (v > m2) { m2 = v; }
    }
    const float gsum = m1 + m2;

    // gather all 8 group sums
    float gsv[NGROUP];
#pragma unroll
    for (int g = 0; g < NGROUP; ++g) gsv[g] = __shfl(gsum, base + g);

    // top-4 groups, redundantly on every lane (identical result, ties->low idx)
    unsigned selmask = 0;
#pragma unroll
    for (int r = 0; r < TOPK_GROUP; ++r) {
      float best = -1e30f; int bg = 0;
#pragma unroll
      for (int g = 0; g < NGROUP; ++g) {
        if (((selmask >> g) & 1u) == 0 && gsv[g] > best) { best = gsv[g]; bg = g; }
      }
      selmask |= 1u << bg;
    }

    // masked candidates for my group (not selected -> 0.0, matches jnp.where)
    const bool gsel = (selmask >> tpt) & 1u;
    float mv[GSIZE];
#pragma unroll
    for (int j = 0; j < GSIZE; ++j) mv[j] = gsel ? lv[j] : 0.0f;

    // 8 argmax rounds; lowest index wins ties (matches ascending > scan)
    unsigned mymask = 0;
    int my_idx = 0;
    float my_w = 0.f, wsum = 0.f;
    for (int r = 0; r < TOPK; ++r) {
      float best = -1e30f; int bj = 0;
#pragma unroll
      for (int j = 0; j < GSIZE; ++j) {
        if ((mymask >> j) & 1u) continue;
        if (mv[j] > best) { best = mv[j]; bj = j; }
      }
      int bidx = tpt * GSIZE + bj;
#pragma unroll
      for (int d = 1; d < 8; d <<= 1) {
        const float ov = __shfl_xor(best, d);
        const int oi = __shfl_xor(bidx, d);
        if (ov > best || (ov == best && oi < bidx)) { best = ov; bidx = oi; }
      }
      if ((bidx >> 5) == tpt) mymask |= 1u << (bidx & 31);
      const float s = sm.val[tok][bidx] - sbias[bidx];  // broadcast read
      wsum += s;
      if (tpt == r) { my_idx = bidx; my_w = s; }
    }
    const float inv = SCALE / (wsum + 1e-20f);
    out_idx[(t0 + tok) * TOPK + tpt] = (float)my_idx;   // tpt == output slot r
    out_w[(t0 + tok) * TOPK + tpt] = my_w * inv;
  }
}

extern "C" void kernel_launch(void* const* d_in, const int* in_sizes, int n_in,
                              void* d_out, int out_size, void* d_ws, size_t ws_size,
                              hipStream_t stream) {
  const float* x = (const float*)d_in[0];     // (4,4096,4096) fp32
  const float* w = (const float*)d_in[1];     // (256,4096) fp32
  const float* bias = (const float*)d_in[2];  // (256,) fp32

  const int T = in_sizes[0] / H;              // 16384
  _Float16* wswz = (_Float16*)d_ws;           // 4 MB frag-linear hi/lo W
  float* out_idx = (float*)d_out;
  float* out_w = (float*)d_out + (size_t)T * TOPK;

  prep_w_kernel<<<dim3(NK16, E / 32), dim3(64), 0, stream>>>(w, wswz);
  moe_gate_kernel<<<dim3(T / BM), dim3(NTH), 0, stream>>>(x, wswz, bias, out_idx, out_w);
}